// Round 1
// baseline (416.591 us; speedup 1.0000x reference)
//
#include <hip/hip_runtime.h>

#define IN_DIM 128
#define HID 64

// ---------- small utility kernels ----------

__global__ void zero_int_kernel(int* p, int n) {
    int i = blockIdx.x * blockDim.x + threadIdx.x;
    if (i < n) p[i] = 0;
}

// Detect whether edge_index is stored as int64 (odd int32 words all zero) or int32.
__global__ void detect_kernel(const int* ei, int* flag) {
    if (threadIdx.x == 0 && blockIdx.x == 0) {
        int is64 = 1;
        for (int i = 1; i < 256; i += 2)
            if (ei[i] != 0) { is64 = 0; break; }
        *flag = is64;
    }
}

// Convert edge_index (either width) to int32 array of 2E entries.
__global__ void convert_kernel(const void* ei, const int* __restrict__ flag, int* out, int n2) {
    int i = blockIdx.x * blockDim.x + threadIdx.x;
    if (i < n2) {
        out[i] = (*flag) ? (int)((const long long*)ei)[i] : ((const int*)ei)[i];
    }
}

// Histogram of dst -> cnt
__global__ void hist_kernel(const int* __restrict__ dst, int E, int* cnt) {
    int i = blockIdx.x * blockDim.x + threadIdx.x;
    if (i < E) atomicAdd(&cnt[dst[i]], 1);
}

// Single-block exclusive scan of cnt -> off; also dinv[i] = rsqrt(cnt[i]+1)  (+1 = self loop)
__global__ __launch_bounds__(1024) void scan_kernel(const int* __restrict__ cnt, int N,
                                                    int* __restrict__ off, float* __restrict__ dinv) {
    __shared__ int ls[1024];
    int t = threadIdx.x;
    int C = (N + 1023) / 1024;
    int lo = t * C;
    int hi = lo + C; if (hi > N) hi = N;
    int s = 0;
    for (int i = lo; i < hi; ++i) s += cnt[i];
    ls[t] = s;
    __syncthreads();
    for (int st = 1; st < 1024; st <<= 1) {
        int v = (t >= st) ? ls[t - st] : 0;
        __syncthreads();
        ls[t] += v;
        __syncthreads();
    }
    int run = ls[t] - s;  // exclusive prefix
    for (int i = lo; i < hi; ++i) {
        off[i] = run;
        int c = cnt[i];
        run += c;
        dinv[i] = rsqrtf((float)(c + 1));
    }
    if (t == 1023) off[N] = run;  // == E
}

// Fill CSR: csr[off[d] + cursor[d]++] = s
__global__ void fill_kernel(const int* __restrict__ src, const int* __restrict__ dst, int E,
                            const int* __restrict__ off, int* cur, int* __restrict__ csr) {
    int i = blockIdx.x * blockDim.x + threadIdx.x;
    if (i < E) {
        int d = dst[i];
        int p = off[d] + atomicAdd(&cur[d], 1);
        csr[p] = src[i];
    }
}

// g1 = dinv ⊙ (x @ W1).  Block: 32 rows x 64 cols; 256 threads, each 8 rows x 1 col.
__global__ __launch_bounds__(256) void gemm1_kernel(const float* __restrict__ x, const float* __restrict__ W1,
                                                    const float* __restrict__ dinv, float* __restrict__ g1, int N) {
    __shared__ float ws[IN_DIM * HID];   // 32 KB
    __shared__ float xs[32][IN_DIM];     // 16 KB
    int t = threadIdx.x;
    for (int i = t; i < IN_DIM * HID / 4; i += 256)
        ((float4*)ws)[i] = ((const float4*)W1)[i];
    int row0 = blockIdx.x * 32;
    for (int i = t; i < 32 * IN_DIM / 4; i += 256) {
        int r = i >> 5;          // 32 float4 per row
        int c4 = i & 31;
        float4 v = make_float4(0.f, 0.f, 0.f, 0.f);
        if (row0 + r < N) v = ((const float4*)x)[(size_t)(row0 + r) * (IN_DIM / 4) + c4];
        *(float4*)&xs[r][c4 * 4] = v;
    }
    __syncthreads();
    int tx = t & 63, ty = t >> 6;
    float acc[8] = {0.f, 0.f, 0.f, 0.f, 0.f, 0.f, 0.f, 0.f};
#pragma unroll 4
    for (int k = 0; k < IN_DIM; ++k) {
        float w = ws[k * HID + tx];          // coalesced, 2 lanes/bank -> free
#pragma unroll
        for (int j = 0; j < 8; ++j)
            acc[j] = fmaf(xs[ty + 4 * j][k], w, acc[j]);  // wave-uniform broadcast
    }
#pragma unroll
    for (int j = 0; j < 8; ++j) {
        int r = row0 + ty + 4 * j;
        if (r < N) g1[(size_t)r * HID + tx] = dinv[r] * acc[j];
    }
}

// Layer-1 aggregation (one wave per node, lane = feature) fused with
// relu + (h1 @ W2) wave-reduction -> g2[v] = dinv[v] * (relu(out1) @ W2)
__global__ __launch_bounds__(256) void gather1_kernel(const float* __restrict__ g1, const int* __restrict__ off,
                                                      const int* __restrict__ csr, const float* __restrict__ dinv,
                                                      const float* __restrict__ b1, const float* __restrict__ W2,
                                                      float* __restrict__ g2, int N) {
    int wid = threadIdx.x >> 6;
    int lane = threadIdx.x & 63;
    int v = blockIdx.x * 4 + wid;
    if (v >= N) return;
    int s = off[v], e = off[v + 1];
    float acc = g1[(size_t)v * HID + lane];      // self loop
    for (int i = s; i < e; ++i) {
        int u = csr[i];                          // wave-uniform broadcast load
        acc += g1[(size_t)u * HID + lane];       // coalesced 256B row
    }
    float dv = dinv[v];
    float h = fmaxf(fmaf(dv, acc, b1[lane]), 0.0f);   // out1 = dinv*acc + b1, relu
    float p = h * W2[lane];
#pragma unroll
    for (int o = 32; o > 0; o >>= 1) p += __shfl_down(p, o, 64);
    if (lane == 0) g2[v] = dv * p;
}

// Layer-2 aggregation on scalars: out[v] = dinv[v]*(g2[v] + sum g2[u]) + b2
__global__ __launch_bounds__(256) void gather2_kernel(const float* __restrict__ g2, const int* __restrict__ off,
                                                      const int* __restrict__ csr, const float* __restrict__ dinv,
                                                      const float* __restrict__ b2, float* __restrict__ out, int N) {
    int wid = threadIdx.x >> 6;
    int lane = threadIdx.x & 63;
    int v = blockIdx.x * 4 + wid;
    if (v >= N) return;
    int s = off[v], e = off[v + 1];
    float p = 0.f;
    for (int i = s + lane; i < e; i += 64) p += g2[csr[i]];
#pragma unroll
    for (int o = 32; o > 0; o >>= 1) p += __shfl_down(p, o, 64);
    if (lane == 0) out[v] = fmaf(dinv[v], g2[v] + p, b2[0]);
}

extern "C" void kernel_launch(void* const* d_in, const int* in_sizes, int n_in,
                              void* d_out, int out_size, void* d_ws, size_t ws_size,
                              hipStream_t stream) {
    const float* x  = (const float*)d_in[0];
    const void*  ei = d_in[1];
    const float* W1 = (const float*)d_in[2];
    const float* b1 = (const float*)d_in[3];
    const float* W2 = (const float*)d_in[4];
    const float* b2 = (const float*)d_in[5];
    float* out = (float*)d_out;

    int N = in_sizes[0] / IN_DIM;
    int E = in_sizes[1] / 2;

    char* w = (char*)d_ws;
    size_t o = 0;
    auto alloc = [&](size_t bytes) { char* p = w + o; o = (o + bytes + 255) & ~(size_t)255; return p; };
    int*   flag = (int*)  alloc(sizeof(int));
    int*   ei32 = (int*)  alloc((size_t)2 * E * sizeof(int));
    int*   off  = (int*)  alloc((size_t)(N + 1) * sizeof(int));
    int*   cnt  = (int*)  alloc((size_t)N * sizeof(int));
    float* dinv = (float*)alloc((size_t)N * sizeof(float));
    int*   csr  = (int*)  alloc((size_t)E * sizeof(int));
    float* g1   = (float*)alloc((size_t)N * HID * sizeof(float));
    float* g2   = (float*)alloc((size_t)N * sizeof(float));
    (void)ws_size; (void)n_in; (void)out_size;

    const int tb = 256;
    int n2 = 2 * E;

    detect_kernel<<<1, 64, 0, stream>>>((const int*)ei, flag);
    convert_kernel<<<(n2 + tb - 1) / tb, tb, 0, stream>>>(ei, flag, ei32, n2);
    const int* src = ei32;
    const int* dst = ei32 + E;

    zero_int_kernel<<<(N + tb - 1) / tb, tb, 0, stream>>>(cnt, N);
    hist_kernel<<<(E + tb - 1) / tb, tb, 0, stream>>>(dst, E, cnt);
    scan_kernel<<<1, 1024, 0, stream>>>(cnt, N, off, dinv);
    zero_int_kernel<<<(N + tb - 1) / tb, tb, 0, stream>>>(cnt, N);
    fill_kernel<<<(E + tb - 1) / tb, tb, 0, stream>>>(src, dst, E, off, cnt, csr);
    gemm1_kernel<<<(N + 31) / 32, 256, 0, stream>>>(x, W1, dinv, g1, N);
    gather1_kernel<<<(N + 3) / 4, 256, 0, stream>>>(g1, off, csr, dinv, b1, W2, g2, N);
    gather2_kernel<<<(N + 3) / 4, 256, 0, stream>>>(g2, off, csr, dinv, b2, out, N);
}

// Round 2
// 271.224 us; speedup vs baseline: 1.5360x; 1.5360x over previous
//
#include <hip/hip_runtime.h>

#define IN_DIM 128
#define HID 64

// Detect whether edge_index is stored as int64 (odd int32 words all zero) or int32.
__global__ void detect_kernel(const int* ei, int* flag) {
    if (threadIdx.x == 0 && blockIdx.x == 0) {
        int is64 = 1;
        for (int i = 1; i < 256; i += 2)
            if (ei[i] != 0) { is64 = 0; break; }
        *flag = is64;
    }
}

// Convert edge_index (either width) to int32 array of 2E entries, and histogram dst.
__global__ void convert_hist_kernel(const void* ei, const int* __restrict__ flag,
                                    int* __restrict__ out, int* cnt, int E) {
    int i = blockIdx.x * blockDim.x + threadIdx.x;
    int n2 = 2 * E;
    if (i < n2) {
        int v = (*flag) ? (int)((const long long*)ei)[i] : ((const int*)ei)[i];
        out[i] = v;
        if (i >= E) atomicAdd(&cnt[v], 1);  // dst half -> degree histogram
    }
}

// ---- hierarchical exclusive scan of cnt[N] -> off[N+1], plus dinv = rsqrt(cnt+1) ----

// Phase A: per-block (256-element) sums.
__global__ __launch_bounds__(256) void scanA_kernel(const int* __restrict__ cnt, int N,
                                                    int* __restrict__ bsum) {
    __shared__ int red[4];
    int i = blockIdx.x * 256 + threadIdx.x;
    int v = (i < N) ? cnt[i] : 0;
#pragma unroll
    for (int o = 32; o > 0; o >>= 1) v += __shfl_down(v, o, 64);
    int w = threadIdx.x >> 6, lane = threadIdx.x & 63;
    if (lane == 0) red[w] = v;
    __syncthreads();
    if (threadIdx.x == 0) bsum[blockIdx.x] = red[0] + red[1] + red[2] + red[3];
}

// Phase B: single-block exclusive scan of up to 1024 block sums; writes off[N] = E.
__global__ __launch_bounds__(1024) void scanB_kernel(const int* __restrict__ bsum, int nb,
                                                     int* __restrict__ boff, int* __restrict__ off, int N) {
    __shared__ int ls[1024];
    int t = threadIdx.x;
    int v = (t < nb) ? bsum[t] : 0;
    ls[t] = v;
    __syncthreads();
    for (int st = 1; st < 1024; st <<= 1) {
        int a = (t >= st) ? ls[t - st] : 0;
        __syncthreads();
        ls[t] += a;
        __syncthreads();
    }
    if (t < nb) boff[t] = ls[t] - v;   // exclusive
    if (t == 1023) off[N] = ls[1023];  // total == E
}

// Phase C: local exclusive scan per 256-chunk + block offset; also dinv.
__global__ __launch_bounds__(256) void scanC_kernel(const int* __restrict__ cnt, int N,
                                                    const int* __restrict__ boff,
                                                    int* __restrict__ off, float* __restrict__ dinv) {
    __shared__ int ls[256];
    int t = threadIdx.x;
    int i = blockIdx.x * 256 + t;
    int c = (i < N) ? cnt[i] : 0;
    ls[t] = c;
    __syncthreads();
    for (int st = 1; st < 256; st <<= 1) {
        int a = (t >= st) ? ls[t - st] : 0;
        __syncthreads();
        ls[t] += a;
        __syncthreads();
    }
    if (i < N) {
        off[i] = boff[blockIdx.x] + ls[t] - c;
        dinv[i] = rsqrtf((float)(c + 1));
    }
}

// Fill CSR: csr[off[d] + cursor[d]++] = s
__global__ void fill_kernel(const int* __restrict__ src, const int* __restrict__ dst, int E,
                            const int* __restrict__ off, int* cur, int* __restrict__ csr) {
    int i = blockIdx.x * blockDim.x + threadIdx.x;
    if (i < E) {
        int d = dst[i];
        int p = off[d] + atomicAdd(&cur[d], 1);
        csr[p] = src[i];
    }
}

// g1 = dinv ⊙ (x @ W1).  Block: 32 rows x 64 cols; 256 threads, each 8 rows x 1 col.
__global__ __launch_bounds__(256) void gemm1_kernel(const float* __restrict__ x, const float* __restrict__ W1,
                                                    const float* __restrict__ dinv, float* __restrict__ g1, int N) {
    __shared__ float ws[IN_DIM * HID];   // 32 KB, layout [k][64]
    __shared__ float xs[32][IN_DIM];     // 16 KB
    int t = threadIdx.x;
    for (int i = t; i < IN_DIM * HID / 4; i += 256)
        ((float4*)ws)[i] = ((const float4*)W1)[i];
    int row0 = blockIdx.x * 32;
    for (int i = t; i < 32 * IN_DIM / 4; i += 256) {
        int r = i >> 5;          // 32 float4 per row
        int c4 = i & 31;
        float4 v = make_float4(0.f, 0.f, 0.f, 0.f);
        if (row0 + r < N) v = ((const float4*)x)[(size_t)(row0 + r) * (IN_DIM / 4) + c4];
        *(float4*)&xs[r][c4 * 4] = v;
    }
    __syncthreads();
    int tx = t & 63, ty = t >> 6;
    float acc[8] = {0.f, 0.f, 0.f, 0.f, 0.f, 0.f, 0.f, 0.f};
    const float4* xs4 = (const float4*)xs;  // xs4[r*32 + k4]
#pragma unroll 8
    for (int k4 = 0; k4 < 32; ++k4) {
        // 4 conflict-free b32 reads of W column tx for k = 4*k4..4*k4+3
        float w0 = ws[(4 * k4 + 0) * HID + tx];
        float w1 = ws[(4 * k4 + 1) * HID + tx];
        float w2 = ws[(4 * k4 + 2) * HID + tx];
        float w3 = ws[(4 * k4 + 3) * HID + tx];
#pragma unroll
        for (int j = 0; j < 8; ++j) {
            float4 xv = xs4[(ty + 4 * j) * 32 + k4];  // wave-uniform broadcast b128
            acc[j] = fmaf(xv.x, w0, acc[j]);
            acc[j] = fmaf(xv.y, w1, acc[j]);
            acc[j] = fmaf(xv.z, w2, acc[j]);
            acc[j] = fmaf(xv.w, w3, acc[j]);
        }
    }
#pragma unroll
    for (int j = 0; j < 8; ++j) {
        int r = row0 + ty + 4 * j;
        if (r < N) g1[(size_t)r * HID + tx] = dinv[r] * acc[j];
    }
}

// Layer-1 aggregation (one wave per node, lane = feature) fused with
// relu + (h1 @ W2) wave-reduction -> g2[v] = dinv[v] * (relu(out1) @ W2)
__global__ __launch_bounds__(256) void gather1_kernel(const float* __restrict__ g1, const int* __restrict__ off,
                                                      const int* __restrict__ csr, const float* __restrict__ dinv,
                                                      const float* __restrict__ b1, const float* __restrict__ W2,
                                                      float* __restrict__ g2, int N) {
    int wid = threadIdx.x >> 6;
    int lane = threadIdx.x & 63;
    int v = blockIdx.x * 4 + wid;
    if (v >= N) return;
    int s = off[v], e = off[v + 1];
    float acc = g1[(size_t)v * HID + lane];      // self loop
    int i = s;
    for (; i + 4 <= e; i += 4) {                 // 4 independent 256B row loads in flight
        int u0 = csr[i], u1 = csr[i + 1], u2 = csr[i + 2], u3 = csr[i + 3];
        float a0 = g1[(size_t)u0 * HID + lane];
        float a1 = g1[(size_t)u1 * HID + lane];
        float a2 = g1[(size_t)u2 * HID + lane];
        float a3 = g1[(size_t)u3 * HID + lane];
        acc += (a0 + a1) + (a2 + a3);
    }
    for (; i < e; ++i) acc += g1[(size_t)csr[i] * HID + lane];
    float dv = dinv[v];
    float h = fmaxf(fmaf(dv, acc, b1[lane]), 0.0f);   // out1 = dinv*acc + b1, relu
    float p = h * W2[lane];
#pragma unroll
    for (int o = 32; o > 0; o >>= 1) p += __shfl_down(p, o, 64);
    if (lane == 0) g2[v] = dv * p;
}

// Layer-2 aggregation on scalars: out[v] = dinv[v]*(g2[v] + sum g2[u]) + b2
__global__ __launch_bounds__(256) void gather2_kernel(const float* __restrict__ g2, const int* __restrict__ off,
                                                      const int* __restrict__ csr, const float* __restrict__ dinv,
                                                      const float* __restrict__ b2, float* __restrict__ out, int N) {
    int wid = threadIdx.x >> 6;
    int lane = threadIdx.x & 63;
    int v = blockIdx.x * 4 + wid;
    if (v >= N) return;
    int s = off[v], e = off[v + 1];
    float p = 0.f;
    for (int i = s + lane; i < e; i += 64) p += g2[csr[i]];
#pragma unroll
    for (int o = 32; o > 0; o >>= 1) p += __shfl_down(p, o, 64);
    if (lane == 0) out[v] = fmaf(dinv[v], g2[v] + p, b2[0]);
}

extern "C" void kernel_launch(void* const* d_in, const int* in_sizes, int n_in,
                              void* d_out, int out_size, void* d_ws, size_t ws_size,
                              hipStream_t stream) {
    const float* x  = (const float*)d_in[0];
    const void*  ei = d_in[1];
    const float* W1 = (const float*)d_in[2];
    const float* b1 = (const float*)d_in[3];
    const float* W2 = (const float*)d_in[4];
    const float* b2 = (const float*)d_in[5];
    float* out = (float*)d_out;

    int N = in_sizes[0] / IN_DIM;
    int E = in_sizes[1] / 2;

    char* w = (char*)d_ws;
    size_t o = 0;
    auto alloc = [&](size_t bytes) { char* p = w + o; o = (o + bytes + 255) & ~(size_t)255; return p; };
    int*   flag = (int*)  alloc(sizeof(int));
    int*   ei32 = (int*)  alloc((size_t)2 * E * sizeof(int));
    int*   off  = (int*)  alloc((size_t)(N + 1) * sizeof(int));
    int*   cnt  = (int*)  alloc((size_t)N * sizeof(int));
    float* dinv = (float*)alloc((size_t)N * sizeof(float));
    int*   csr  = (int*)  alloc((size_t)E * sizeof(int));
    float* g1   = (float*)alloc((size_t)N * HID * sizeof(float));
    float* g2   = (float*)alloc((size_t)N * sizeof(float));
    int*   bsum = (int*)  alloc(1024 * sizeof(int));
    int*   boff = (int*)  alloc(1024 * sizeof(int));
    (void)ws_size; (void)n_in; (void)out_size;

    const int tb = 256;
    int n2 = 2 * E;
    int nbs = (N + 255) / 256;  // scan blocks (196 for N=50000; scanB supports <=1024)

    detect_kernel<<<1, 64, 0, stream>>>((const int*)ei, flag);
    hipMemsetAsync(cnt, 0, (size_t)N * sizeof(int), stream);
    convert_hist_kernel<<<(n2 + tb - 1) / tb, tb, 0, stream>>>(ei, flag, ei32, cnt, E);
    const int* src = ei32;
    const int* dst = ei32 + E;

    scanA_kernel<<<nbs, 256, 0, stream>>>(cnt, N, bsum);
    scanB_kernel<<<1, 1024, 0, stream>>>(bsum, nbs, boff, off, N);
    scanC_kernel<<<nbs, 256, 0, stream>>>(cnt, N, boff, off, dinv);

    hipMemsetAsync(cnt, 0, (size_t)N * sizeof(int), stream);  // reuse as cursor
    fill_kernel<<<(E + tb - 1) / tb, tb, 0, stream>>>(src, dst, E, off, cnt, csr);
    gemm1_kernel<<<(N + 31) / 32, 256, 0, stream>>>(x, W1, dinv, g1, N);
    gather1_kernel<<<(N + 3) / 4, 256, 0, stream>>>(g1, off, csr, dinv, b1, W2, g2, N);
    gather2_kernel<<<(N + 3) / 4, 256, 0, stream>>>(g2, off, csr, dinv, b2, out, N);
}